// Round 21
// baseline (75.667 us; speedup 1.0000x reference)
//
#include <hip/hip_runtime.h>

#define NN 5000
#define NF 4
#define NT 12
#define NC 600
#define NCP 640   // padded d-extent (zero pad -> r=0, no predication)
#define NE 160000
#define FT 48   // NF*NT
#define LOG2E 1.4426950408889634f

typedef float v2f __attribute__((ext_vector_type(2)));

// ws layout (float offsets):
//   cnt   [0,     5000)    int   (zeroed by k_init)
//   base  [5000, 10001)    int   (pad to 10008)
//   rank  [10008,170008)   int
//   epak  [170008,490008)  int2 (src, w-bits) per bucketed edge
//   dis   [490008,495008)
//   tabG  [495008,509100)  packed PADDED tables (zeroed by k_init):
//     mz4   [0,2560)       float4[640] (LOG2E-scaled)
//     mh4   [2560,5120)    float4[640] (2*LOG2E-scaled)
//     bzh   [5120,6400)    float2[640] (betaz,betah)
//     wt    [6400,14080)   float4[3][640]: wt[q][d][j] = Whead[4q+j][d]
//     probs [14080,14092)

// zero cnt (5000 words) and tabG (14092 words)
__global__ void k_init(int* __restrict__ cnt, float* __restrict__ tabG) {
    int i = blockIdx.x * blockDim.x + threadIdx.x;
    if (i < 5000) cnt[i] = 0;
    else if (i < 19092) tabG[i - 5000] = 0.f;
}

// Fused: blocks [0,625) rank histogram (int atomic only);
//        blocks [625,...) weight composition into tabG (independent work).
#define CNT_BLOCKS 625
#define WB_WAVES 6132   // 6000 table + 12 probs + 120 wt-repack
__global__ __launch_bounds__(256) void k_count(
        const int* __restrict__ ei,
        int* __restrict__ cnt, int* __restrict__ rank,
        const float* __restrict__ Wz, const float* __restrict__ bz,
        const float* __restrict__ Wh, const float* __restrict__ bh,
        const float* __restrict__ Wlz, const float* __restrict__ blz,
        const float* __restrict__ Wlh, const float* __restrict__ blh,
        const float* __restrict__ att, const float* __restrict__ Whead,
        float* __restrict__ tabG) {
    int bid = blockIdx.x;
    int tid = threadIdx.x;
    if (bid < CNT_BLOCKS) {
        int e = bid * 256 + tid;
        if (e < NE) rank[e] = atomicAdd(&cnt[ei[NE + e]], 1);
        return;
    }
    int wid = (bid - CNT_BLOCKS) * 4 + (tid >> 6);
    int lane = tid & 63;
    if (wid >= WB_WAVES) return;

    if (wid < 6000) {
        const float* va;
        const float* vb;
        float scale, bias = 0.f;
        if (wid < 2400) {
            int f = wid / NC, d = wid % NC;
            va = Wz + f * NC; vb = Wlz + d * (2 * NC); scale = LOG2E;
        } else if (wid < 4800) {
            int j = wid - 2400;
            int f = j / NC, d = j % NC;
            va = Wh + f * NC; vb = Wlh + d * (2 * NC); scale = 2.0f * LOG2E;
        } else if (wid < 5400) {
            int d = wid - 4800;
            va = bz; vb = Wlz + d * (2 * NC); scale = LOG2E; bias = blz[d];
        } else {
            int d = wid - 5400;
            va = bh; vb = Wlh + d * (2 * NC); scale = 2.0f * LOG2E; bias = blh[d];
        }
        float s = 0.f;
        for (int c = lane; c < NC; c += 64) s = fmaf(va[c], vb[c], s);
#pragma unroll
        for (int off = 32; off > 0; off >>= 1) s += __shfl_down(s, off, 64);
        if (lane == 0) {
            float r = scale * (bias + s);
            if (wid < 2400) {
                int f = wid / NC, d = wid % NC;
                tabG[d * 4 + f] = r;
            } else if (wid < 4800) {
                int j = wid - 2400;
                int f = j / NC, d = j % NC;
                tabG[2560 + d * 4 + f] = r;
            } else if (wid < 5400) {
                tabG[5120 + (wid - 4800) * 2] = r;
            } else {
                tabG[5120 + (wid - 5400) * 2 + 1] = r;
            }
        }
    } else if (wid < 6012) {
        if (lane == 0) {
            int t = wid - 6000;
            float m = att[0];
            for (int k = 1; k < NT; ++k) m = fmaxf(m, att[k]);
            float ssum = 0.f;
            for (int k = 0; k < NT; ++k) ssum += __expf(att[k] - m);
            tabG[14080 + t] = __expf(att[t] - m) / ssum;
        }
    } else {
        int i = (wid - 6012) * 64 + lane;   // [0,7680)
        if (i < 7680) {
            int j = i & 3;
            int rest = i >> 2;          // [0,1920)
            int d = rest % NCP, q = rest / NCP;
            float v = (d < NC) ? Whead[(4 * q + j) * NC + d] : 0.f;
            tabG[6400 + i] = v;
        }
    }
}

// single-block exclusive scan of cnt -> base
#define SCAN_CHUNK 20
__global__ __launch_bounds__(256) void k_scan(const int* __restrict__ cnt,
                                              int* __restrict__ base) {
    __shared__ int part[256];
    int t = threadIdx.x;
    int start = t * SCAN_CHUNK;
    int s = 0;
#pragma unroll
    for (int k = 0; k < SCAN_CHUNK; ++k) {
        int idx = start + k;
        if (idx < NN) s += cnt[idx];
    }
    part[t] = s;
    __syncthreads();
    for (int off = 1; off < 256; off <<= 1) {
        int v = (t >= off) ? part[t - off] : 0;
        __syncthreads();
        part[t] += v;
        __syncthreads();
    }
    int running = (t == 0) ? 0 : part[t - 1];
#pragma unroll
    for (int k = 0; k < SCAN_CHUNK; ++k) {
        int idx = start + k;
        if (idx < NN) {
            base[idx] = running;
            running += cnt[idx];
        }
    }
    if (t == 255) base[NN] = part[255];
}

// deterministic-position scatter of packed (src, weight): one 8B store
__global__ void k_scatter(const int* __restrict__ ei, const float* __restrict__ w,
                          const int* __restrict__ base, const int* __restrict__ rank,
                          int2* __restrict__ epak) {
    int e = blockIdx.x * blockDim.x + threadIdx.x;
    if (e < NE) {
        int2 p; p.x = ei[e]; p.y = __float_as_int(w[e]);
        epak[base[ei[NE + e]] + rank[e]] = p;
    }
}

// per-node degree from packed edges (sequential reads), dis = rsqrt(1+deg)
__global__ __launch_bounds__(64) void k_deg_dis(const int2* __restrict__ epak,
                                                const int* __restrict__ base,
                                                float* __restrict__ dis) {
    int n = blockIdx.x;
    int lane = threadIdx.x;
    int b0 = base[n], b1 = base[n + 1];
    float s = 0.f;
    for (int j = b0 + lane; j < b1; j += 64) s += __int_as_float(epak[j].y);
#pragma unroll
    for (int off = 32; off > 0; off >>= 1) s += __shfl_down(s, off, 64);
    if (lane == 0) dis[n] = rsqrtf(1.0f + s);
}

// FUSED gather + gate + attention + head. 1250 blocks x 4 waves; wave = node.
// Phase 1 (gather): lane ft holds agg[n][ft] in acc (R14 k_gather body).
// Phase 2 (gate): agg row broadcast to SGPRs via v_readlane; gate tables
// mz4/mh4/bzh (25.6 KB) staged in LDS once per block so the remaining
// L1-side working set (wt, 30 KB) fits the 32 KB L1 -> no L2 table stream.
__global__ __launch_bounds__(256, 3) void k_node(
        const float* __restrict__ x, const float* __restrict__ dis,
        const int2* __restrict__ epak, const int* __restrict__ base,
        const float* __restrict__ tabG,
        const float* __restrict__ bhead, float* __restrict__ out) {
    __shared__ float tabS[6400];   // mz4 [0,2560) | mh4 [2560,5120) | bzh [5120,6400)
    __shared__ float red[4][NT][16];
    int tid = threadIdx.x;

    // stage gate tables (1600 float4 = 25.6 KB), once per block
    {
        const float4* s4 = (const float4*)tabG;
        float4* d4 = (float4*)tabS;
        for (int i = tid; i < 1600; i += 256) d4[i] = s4[i];
    }
    __syncthreads();

    int wid = __builtin_amdgcn_readfirstlane(tid >> 6);
    int lane = tid & 63;
    int n = blockIdx.x * 4 + wid;   // uniform

    // ---- phase 1: gather (same memory pattern as R14 k_gather) ----
    int b0 = base[n], b1 = base[n + 1];
    float dn = dis[n];
    float acc = 0.f;
    if (lane < FT) acc = dn * x[n * FT + lane];
    int j = b0;
    for (; j + 3 < b1; j += 4) {
        int2 p0 = epak[j], p1 = epak[j + 1], p2 = epak[j + 2], p3 = epak[j + 3];
        float n0 = dis[p0.x] * __int_as_float(p0.y);
        float n1 = dis[p1.x] * __int_as_float(p1.y);
        float n2 = dis[p2.x] * __int_as_float(p2.y);
        float n3 = dis[p3.x] * __int_as_float(p3.y);
        if (lane < FT) {
            acc += n0 * x[p0.x * FT + lane];
            acc += n1 * x[p1.x * FT + lane];
            acc += n2 * x[p2.x * FT + lane];
            acc += n3 * x[p3.x * FT + lane];
        }
    }
    for (; j < b1; ++j) {
        int2 p0 = epak[j];
        float n0 = dis[p0.x] * __int_as_float(p0.y);
        if (lane < FT) acc += n0 * x[p0.x * FT + lane];
    }
    acc *= dn;   // lane ft (ft<48) now holds agg[n][ft]

    // ---- broadcast agg row to wave-uniform scalars (SGPRs) ----
    v2f A2[24];
#pragma unroll
    for (int i = 0; i < 24; ++i) {
        A2[i].x = __int_as_float(__builtin_amdgcn_readlane(__float_as_int(acc), 2 * i));
        A2[i].y = __int_as_float(__builtin_amdgcn_readlane(__float_as_int(acc), 2 * i + 1));
    }

    // ---- phase 2: gate + attention + head ----
    const float4* mz4 = (const float4*)tabS;
    const float4* mh4 = (const float4*)(tabS + 2560);
    const float2* bzh = (const float2*)(tabS + 5120);
    const float4* wt4 = (const float4*)(tabG + 6400);   // [q*640 + d], L1-resident

    v2f pp[6];
#pragma unroll
    for (int tp = 0; tp < 6; ++tp) { pp[tp].x = tabG[14080 + 2 * tp]; pp[tp].y = tabG[14080 + 2 * tp + 1]; }

    float outp[NT];
#pragma unroll
    for (int t = 0; t < NT; ++t) outp[t] = 0.f;

#pragma unroll
    for (int it = 0; it < 10; ++it) {
        int dd = it * 64 + lane;   // < 640, pad rows are zero -> r = 0

        float4 mzv = mz4[dd];
        float4 mhv = mh4[dd];
        float2 bb = bzh[dd];

        v2f hacc; hacc.x = 0.f; hacc.y = 0.f;
#pragma unroll
        for (int tp = 0; tp < 6; ++tp) {
            v2f u; u.x = bb.x; u.y = bb.x;
            v2f v; v.x = bb.y; v.y = bb.y;
            u += A2[0 * 6 + tp] * mzv.x;
            u += A2[1 * 6 + tp] * mzv.y;
            u += A2[2 * 6 + tp] * mzv.z;
            u += A2[3 * 6 + tp] * mzv.w;
            v += A2[0 * 6 + tp] * mhv.x;
            v += A2[1 * 6 + tp] * mhv.y;
            v += A2[2 * 6 + tp] * mhv.z;
            v += A2[3 * 6 + tp] * mhv.w;
            v2f eu; eu.x = exp2f(u.x); eu.y = exp2f(u.y);
            v2f ev; ev.x = exp2f(v.x); ev.y = exp2f(v.y);
            v2f den = (eu + 1.f) * (ev + 1.f);
            v2f rd; rd.x = __builtin_amdgcn_rcpf(den.x); rd.y = __builtin_amdgcn_rcpf(den.y);
            v2f num = pp[tp] * (ev - 1.f);
            hacc += num * rd;
        }
        float r = fmaxf(hacc.x + hacc.y, 0.f);

        float4 w0 = wt4[0 * NCP + dd], w1 = wt4[1 * NCP + dd], w2 = wt4[2 * NCP + dd];
        outp[0]  = fmaf(r, w0.x, outp[0]);   outp[1]  = fmaf(r, w0.y, outp[1]);
        outp[2]  = fmaf(r, w0.z, outp[2]);   outp[3]  = fmaf(r, w0.w, outp[3]);
        outp[4]  = fmaf(r, w1.x, outp[4]);   outp[5]  = fmaf(r, w1.y, outp[5]);
        outp[6]  = fmaf(r, w1.z, outp[6]);   outp[7]  = fmaf(r, w1.w, outp[7]);
        outp[8]  = fmaf(r, w2.x, outp[8]);   outp[9]  = fmaf(r, w2.y, outp[9]);
        outp[10] = fmaf(r, w2.z, outp[10]);  outp[11] = fmaf(r, w2.w, outp[11]);
    }

    // 2-step shuffle then 16-wide LDS transpose reduce (wave-private)
#pragma unroll
    for (int t = 0; t < NT; ++t) {
        float v = outp[t];
        v += __shfl_xor(v, 32, 64);
        v += __shfl_xor(v, 16, 64);
        if (lane < 16) red[wid][t][lane] = v;
    }
    if (lane < NT) {
        const float4* row = (const float4*)red[wid][lane];
        float4 a = row[0], b = row[1], c = row[2], d = row[3];
        float s = ((a.x + a.y) + (a.z + a.w)) + ((b.x + b.y) + (b.z + b.w))
                + ((c.x + c.y) + (c.z + c.w)) + ((d.x + d.y) + (d.z + d.w));
        out[n * NT + lane] = s + bhead[lane];
    }
}

extern "C" void kernel_launch(void* const* d_in, const int* in_sizes, int n_in,
                              void* d_out, int out_size, void* d_ws, size_t ws_size,
                              hipStream_t stream) {
    const float* x     = (const float*)d_in[0];
    const int*   ei    = (const int*)d_in[1];
    const float* ea    = (const float*)d_in[2];
    const float* Wz    = (const float*)d_in[3];
    const float* bz    = (const float*)d_in[4];
    const float* Wh    = (const float*)d_in[7];
    const float* bh    = (const float*)d_in[8];
    const float* Wlz   = (const float*)d_in[9];
    const float* blz   = (const float*)d_in[10];
    const float* Wlh   = (const float*)d_in[13];
    const float* blh   = (const float*)d_in[14];
    const float* att   = (const float*)d_in[15];
    const float* Whead = (const float*)d_in[16];
    const float* bhead = (const float*)d_in[17];
    float* out = (float*)d_out;

    float* ws   = (float*)d_ws;
    int*   cnt  = (int*)ws;                 // [0,5000)
    int*   base = (int*)(ws + 5000);        // [5000,10008)
    int*   rank = (int*)(ws + 10008);
    int2*  epak = (int2*)(ws + 170008);
    float* dis  = ws + 490008;
    float* tabG = ws + 495008;

    k_init<<<(19092 + 255) / 256, 256, 0, stream>>>(cnt, tabG);
    k_count<<<CNT_BLOCKS + (WB_WAVES + 3) / 4, 256, 0, stream>>>(
        ei, cnt, rank,
        Wz, bz, Wh, bh, Wlz, blz, Wlh, blh, att, Whead, tabG);
    k_scan<<<1, 256, 0, stream>>>(cnt, base);
    k_scatter<<<(NE + 255) / 256, 256, 0, stream>>>(ei, ea, base, rank, epak);
    k_deg_dis<<<NN, 64, 0, stream>>>(epak, base, dis);
    k_node<<<NN / 4, 256, 0, stream>>>(x, dis, epak, base, tabG, bhead, out);
}

// Round 22
// 73.674 us; speedup vs baseline: 1.0270x; 1.0270x over previous
//
#include <hip/hip_runtime.h>

#define NN 5000
#define NF 4
#define NT 12
#define NC 600
#define NCP 640   // padded d-extent (zero pad -> r=0, no predication)
#define NE 160000
#define FT 48   // NF*NT
#define LOG2E 1.4426950408889634f

typedef float v2f __attribute__((ext_vector_type(2)));

// ws layout (float offsets):
//   cnt   [0,     5000)    int   (zeroed by k_init)
//   base  [5000, 10001)    int   (pad to 10008)
//   rank  [10008,170008)   int
//   epak  [170008,490008)  int2 (src, w-bits) per bucketed edge
//   dis   [490008,495008)
//   tabG  [495008,509100)  packed PADDED tables (zeroed by k_init):
//     mz4   [0,2560)       float4[640] (LOG2E-scaled)
//     mh4   [2560,5120)    float4[640] (2*LOG2E-scaled)
//     bzh   [5120,6400)    float2[640] (betaz,betah)
//     wt    [6400,14080)   float4[3][640]: wt[q][d][j] = Whead[4q+j][d]
//     probs [14080,14092)

// zero cnt (5000 words) and tabG (14092 words)
__global__ void k_init(int* __restrict__ cnt, float* __restrict__ tabG) {
    int i = blockIdx.x * blockDim.x + threadIdx.x;
    if (i < 5000) cnt[i] = 0;
    else if (i < 19092) tabG[i - 5000] = 0.f;
}

// Fused: blocks [0,625) rank histogram (int atomic only);
//        blocks [625,...) weight composition into tabG (independent work).
#define CNT_BLOCKS 625
#define WB_WAVES 6132   // 6000 table + 12 probs + 120 wt-repack
__global__ __launch_bounds__(256) void k_count(
        const int* __restrict__ ei,
        int* __restrict__ cnt, int* __restrict__ rank,
        const float* __restrict__ Wz, const float* __restrict__ bz,
        const float* __restrict__ Wh, const float* __restrict__ bh,
        const float* __restrict__ Wlz, const float* __restrict__ blz,
        const float* __restrict__ Wlh, const float* __restrict__ blh,
        const float* __restrict__ att, const float* __restrict__ Whead,
        float* __restrict__ tabG) {
    int bid = blockIdx.x;
    int tid = threadIdx.x;
    if (bid < CNT_BLOCKS) {
        int e = bid * 256 + tid;
        if (e < NE) rank[e] = atomicAdd(&cnt[ei[NE + e]], 1);
        return;
    }
    int wid = (bid - CNT_BLOCKS) * 4 + (tid >> 6);
    int lane = tid & 63;
    if (wid >= WB_WAVES) return;

    if (wid < 6000) {
        const float* va;
        const float* vb;
        float scale, bias = 0.f;
        if (wid < 2400) {
            int f = wid / NC, d = wid % NC;
            va = Wz + f * NC; vb = Wlz + d * (2 * NC); scale = LOG2E;
        } else if (wid < 4800) {
            int j = wid - 2400;
            int f = j / NC, d = j % NC;
            va = Wh + f * NC; vb = Wlh + d * (2 * NC); scale = 2.0f * LOG2E;
        } else if (wid < 5400) {
            int d = wid - 4800;
            va = bz; vb = Wlz + d * (2 * NC); scale = LOG2E; bias = blz[d];
        } else {
            int d = wid - 5400;
            va = bh; vb = Wlh + d * (2 * NC); scale = 2.0f * LOG2E; bias = blh[d];
        }
        float s = 0.f;
        for (int c = lane; c < NC; c += 64) s = fmaf(va[c], vb[c], s);
#pragma unroll
        for (int off = 32; off > 0; off >>= 1) s += __shfl_down(s, off, 64);
        if (lane == 0) {
            float r = scale * (bias + s);
            if (wid < 2400) {
                int f = wid / NC, d = wid % NC;
                tabG[d * 4 + f] = r;
            } else if (wid < 4800) {
                int j = wid - 2400;
                int f = j / NC, d = j % NC;
                tabG[2560 + d * 4 + f] = r;
            } else if (wid < 5400) {
                tabG[5120 + (wid - 4800) * 2] = r;
            } else {
                tabG[5120 + (wid - 5400) * 2 + 1] = r;
            }
        }
    } else if (wid < 6012) {
        if (lane == 0) {
            int t = wid - 6000;
            float m = att[0];
            for (int k = 1; k < NT; ++k) m = fmaxf(m, att[k]);
            float ssum = 0.f;
            for (int k = 0; k < NT; ++k) ssum += __expf(att[k] - m);
            tabG[14080 + t] = __expf(att[t] - m) / ssum;
        }
    } else {
        int i = (wid - 6012) * 64 + lane;   // [0,7680)
        if (i < 7680) {
            int j = i & 3;
            int rest = i >> 2;          // [0,1920)
            int d = rest % NCP, q = rest / NCP;
            float v = (d < NC) ? Whead[(4 * q + j) * NC + d] : 0.f;
            tabG[6400 + i] = v;
        }
    }
}

// single-block exclusive scan of cnt -> base
#define SCAN_CHUNK 20
__global__ __launch_bounds__(256) void k_scan(const int* __restrict__ cnt,
                                              int* __restrict__ base) {
    __shared__ int part[256];
    int t = threadIdx.x;
    int start = t * SCAN_CHUNK;
    int s = 0;
#pragma unroll
    for (int k = 0; k < SCAN_CHUNK; ++k) {
        int idx = start + k;
        if (idx < NN) s += cnt[idx];
    }
    part[t] = s;
    __syncthreads();
    for (int off = 1; off < 256; off <<= 1) {
        int v = (t >= off) ? part[t - off] : 0;
        __syncthreads();
        part[t] += v;
        __syncthreads();
    }
    int running = (t == 0) ? 0 : part[t - 1];
#pragma unroll
    for (int k = 0; k < SCAN_CHUNK; ++k) {
        int idx = start + k;
        if (idx < NN) {
            base[idx] = running;
            running += cnt[idx];
        }
    }
    if (t == 255) base[NN] = part[255];
}

// deterministic-position scatter of packed (src, weight): one 8B store
__global__ void k_scatter(const int* __restrict__ ei, const float* __restrict__ w,
                          const int* __restrict__ base, const int* __restrict__ rank,
                          int2* __restrict__ epak) {
    int e = blockIdx.x * blockDim.x + threadIdx.x;
    if (e < NE) {
        int2 p; p.x = ei[e]; p.y = __float_as_int(w[e]);
        epak[base[ei[NE + e]] + rank[e]] = p;
    }
}

// per-node degree from packed edges (sequential reads), dis = rsqrt(1+deg)
__global__ __launch_bounds__(64) void k_deg_dis(const int2* __restrict__ epak,
                                                const int* __restrict__ base,
                                                float* __restrict__ dis) {
    int n = blockIdx.x;
    int lane = threadIdx.x;
    int b0 = base[n], b1 = base[n + 1];
    float s = 0.f;
    for (int j = b0 + lane; j < b1; j += 64) s += __int_as_float(epak[j].y);
#pragma unroll
    for (int off = 32; off > 0; off >>= 1) s += __shfl_down(s, off, 64);
    if (lane == 0) dis[n] = rsqrtf(1.0f + s);
}

// FUSED gather + gate + attention + head. 1250 blocks x 4 waves; wave = node.
// Gather is 2-deep software-pipelined: iteration g issues group-g meta
// (epak/dis, SGPR-side) + x-loads, and consumes group g-1's x values --
// x-load latency hides under the next group's issue work. Pipeline meta
// state is wave-uniform (SGPRs), so VGPR demand stays under the lb(256,3)
// 84-cap (R20: 68 VGPR, no spill).
__global__ __launch_bounds__(256, 3) void k_node(
        const float* __restrict__ x, const float* __restrict__ dis,
        const int2* __restrict__ epak, const int* __restrict__ base,
        const float* __restrict__ tabG,
        const float* __restrict__ bhead, float* __restrict__ out) {
    __shared__ float red[4][NT][16];
    int tid = threadIdx.x;
    int wid = __builtin_amdgcn_readfirstlane(tid >> 6);
    int lane = tid & 63;
    int n = blockIdx.x * 4 + wid;   // uniform

    // ---- phase 1: gather, 2-deep pipelined ----
    int b0 = base[n], b1 = base[n + 1];
    float dn = dis[n];
    float acc = 0.f;
    if (lane < FT) acc = dn * x[n * FT + lane];

    int nfull = (b1 - b0) >> 2;
    int j = b0;
    float nu0 = 0.f, nu1 = 0.f, nu2 = 0.f, nu3 = 0.f;
    float xv0 = 0.f, xv1 = 0.f, xv2 = 0.f, xv3 = 0.f;
    if (nfull > 0) {   // prologue: group 0 meta + x-load issue
        int2 p0 = epak[j], p1 = epak[j + 1], p2 = epak[j + 2], p3 = epak[j + 3];
        nu0 = dis[p0.x] * __int_as_float(p0.y);
        nu1 = dis[p1.x] * __int_as_float(p1.y);
        nu2 = dis[p2.x] * __int_as_float(p2.y);
        nu3 = dis[p3.x] * __int_as_float(p3.y);
        if (lane < FT) {
            xv0 = x[p0.x * FT + lane];
            xv1 = x[p1.x * FT + lane];
            xv2 = x[p2.x * FT + lane];
            xv3 = x[p3.x * FT + lane];
        }
        j += 4;
    }
    for (int g = 1; g < nfull; ++g, j += 4) {
        // issue next group's meta + x loads
        int2 q0 = epak[j], q1 = epak[j + 1], q2 = epak[j + 2], q3 = epak[j + 3];
        float mu0 = dis[q0.x] * __int_as_float(q0.y);
        float mu1 = dis[q1.x] * __int_as_float(q1.y);
        float mu2 = dis[q2.x] * __int_as_float(q2.y);
        float mu3 = dis[q3.x] * __int_as_float(q3.y);
        float yv0 = 0.f, yv1 = 0.f, yv2 = 0.f, yv3 = 0.f;
        if (lane < FT) {
            yv0 = x[q0.x * FT + lane];
            yv1 = x[q1.x * FT + lane];
            yv2 = x[q2.x * FT + lane];
            yv3 = x[q3.x * FT + lane];
        }
        // consume previous group (loads issued last iteration)
        acc = fmaf(nu0, xv0, acc);
        acc = fmaf(nu1, xv1, acc);
        acc = fmaf(nu2, xv2, acc);
        acc = fmaf(nu3, xv3, acc);
        nu0 = mu0; nu1 = mu1; nu2 = mu2; nu3 = mu3;
        xv0 = yv0; xv1 = yv1; xv2 = yv2; xv3 = yv3;
    }
    if (nfull > 0) {   // epilogue: consume last full group
        acc = fmaf(nu0, xv0, acc);
        acc = fmaf(nu1, xv1, acc);
        acc = fmaf(nu2, xv2, acc);
        acc = fmaf(nu3, xv3, acc);
    }
    for (; j < b1; ++j) {   // tail (0-3 edges)
        int2 p0 = epak[j];
        float n0 = dis[p0.x] * __int_as_float(p0.y);
        if (lane < FT) acc = fmaf(n0, x[p0.x * FT + lane], acc);
    }
    acc *= dn;   // lane ft (ft<48) now holds agg[n][ft]

    // ---- broadcast agg row to wave-uniform scalars (SGPRs) ----
    v2f A2[24];
#pragma unroll
    for (int i = 0; i < 24; ++i) {
        A2[i].x = __int_as_float(__builtin_amdgcn_readlane(__float_as_int(acc), 2 * i));
        A2[i].y = __int_as_float(__builtin_amdgcn_readlane(__float_as_int(acc), 2 * i + 1));
    }

    // ---- phase 2: gate + attention + head (R20 body, global tables) ----
    const float4* mz4 = (const float4*)tabG;
    const float4* mh4 = (const float4*)(tabG + 2560);
    const float2* bzh = (const float2*)(tabG + 5120);
    const float4* wt4 = (const float4*)(tabG + 6400);   // [q*640 + d]

    v2f pp[6];
#pragma unroll
    for (int tp = 0; tp < 6; ++tp) { pp[tp].x = tabG[14080 + 2 * tp]; pp[tp].y = tabG[14080 + 2 * tp + 1]; }

    float outp[NT];
#pragma unroll
    for (int t = 0; t < NT; ++t) outp[t] = 0.f;

#pragma unroll
    for (int it = 0; it < 10; ++it) {
        int dd = it * 64 + lane;   // < 640, pad rows are zero -> r = 0

        float4 mzv = mz4[dd];
        float4 mhv = mh4[dd];
        float2 bb = bzh[dd];

        v2f hacc; hacc.x = 0.f; hacc.y = 0.f;
#pragma unroll
        for (int tp = 0; tp < 6; ++tp) {
            v2f u; u.x = bb.x; u.y = bb.x;
            v2f v; v.x = bb.y; v.y = bb.y;
            u += A2[0 * 6 + tp] * mzv.x;
            u += A2[1 * 6 + tp] * mzv.y;
            u += A2[2 * 6 + tp] * mzv.z;
            u += A2[3 * 6 + tp] * mzv.w;
            v += A2[0 * 6 + tp] * mhv.x;
            v += A2[1 * 6 + tp] * mhv.y;
            v += A2[2 * 6 + tp] * mhv.z;
            v += A2[3 * 6 + tp] * mhv.w;
            v2f eu; eu.x = exp2f(u.x); eu.y = exp2f(u.y);
            v2f ev; ev.x = exp2f(v.x); ev.y = exp2f(v.y);
            v2f den = (eu + 1.f) * (ev + 1.f);
            v2f rd; rd.x = __builtin_amdgcn_rcpf(den.x); rd.y = __builtin_amdgcn_rcpf(den.y);
            v2f num = pp[tp] * (ev - 1.f);
            hacc += num * rd;
        }
        float r = fmaxf(hacc.x + hacc.y, 0.f);

        float4 w0 = wt4[0 * NCP + dd], w1 = wt4[1 * NCP + dd], w2 = wt4[2 * NCP + dd];
        outp[0]  = fmaf(r, w0.x, outp[0]);   outp[1]  = fmaf(r, w0.y, outp[1]);
        outp[2]  = fmaf(r, w0.z, outp[2]);   outp[3]  = fmaf(r, w0.w, outp[3]);
        outp[4]  = fmaf(r, w1.x, outp[4]);   outp[5]  = fmaf(r, w1.y, outp[5]);
        outp[6]  = fmaf(r, w1.z, outp[6]);   outp[7]  = fmaf(r, w1.w, outp[7]);
        outp[8]  = fmaf(r, w2.x, outp[8]);   outp[9]  = fmaf(r, w2.y, outp[9]);
        outp[10] = fmaf(r, w2.z, outp[10]);  outp[11] = fmaf(r, w2.w, outp[11]);
    }

    // 2-step shuffle then 16-wide LDS transpose reduce (wave-private)
#pragma unroll
    for (int t = 0; t < NT; ++t) {
        float v = outp[t];
        v += __shfl_xor(v, 32, 64);
        v += __shfl_xor(v, 16, 64);
        if (lane < 16) red[wid][t][lane] = v;
    }
    if (lane < NT) {
        const float4* row = (const float4*)red[wid][lane];
        float4 a = row[0], b = row[1], c = row[2], d = row[3];
        float s = ((a.x + a.y) + (a.z + a.w)) + ((b.x + b.y) + (b.z + b.w))
                + ((c.x + c.y) + (c.z + c.w)) + ((d.x + d.y) + (d.z + d.w));
        out[n * NT + lane] = s + bhead[lane];
    }
}

extern "C" void kernel_launch(void* const* d_in, const int* in_sizes, int n_in,
                              void* d_out, int out_size, void* d_ws, size_t ws_size,
                              hipStream_t stream) {
    const float* x     = (const float*)d_in[0];
    const int*   ei    = (const int*)d_in[1];
    const float* ea    = (const float*)d_in[2];
    const float* Wz    = (const float*)d_in[3];
    const float* bz    = (const float*)d_in[4];
    const float* Wh    = (const float*)d_in[7];
    const float* bh    = (const float*)d_in[8];
    const float* Wlz   = (const float*)d_in[9];
    const float* blz   = (const float*)d_in[10];
    const float* Wlh   = (const float*)d_in[13];
    const float* blh   = (const float*)d_in[14];
    const float* att   = (const float*)d_in[15];
    const float* Whead = (const float*)d_in[16];
    const float* bhead = (const float*)d_in[17];
    float* out = (float*)d_out;

    float* ws   = (float*)d_ws;
    int*   cnt  = (int*)ws;                 // [0,5000)
    int*   base = (int*)(ws + 5000);        // [5000,10008)
    int*   rank = (int*)(ws + 10008);
    int2*  epak = (int2*)(ws + 170008);
    float* dis  = ws + 490008;
    float* tabG = ws + 495008;

    k_init<<<(19092 + 255) / 256, 256, 0, stream>>>(cnt, tabG);
    k_count<<<CNT_BLOCKS + (WB_WAVES + 3) / 4, 256, 0, stream>>>(
        ei, cnt, rank,
        Wz, bz, Wh, bh, Wlz, blz, Wlh, blh, att, Whead, tabG);
    k_scan<<<1, 256, 0, stream>>>(cnt, base);
    k_scatter<<<(NE + 255) / 256, 256, 0, stream>>>(ei, ea, base, rank, epak);
    k_deg_dis<<<NN, 64, 0, stream>>>(epak, base, dis);
    k_node<<<NN / 4, 256, 0, stream>>>(x, dis, epak, base, tabG, bhead, out);
}

// Round 23
// 72.382 us; speedup vs baseline: 1.0454x; 1.0178x over previous
//
#include <hip/hip_runtime.h>

#define NN 5000
#define NF 4
#define NT 12
#define NC 600
#define NCP 640   // padded d-extent (zero pad -> r=0, no predication)
#define NE 160000
#define FT 48   // NF*NT
#define LOG2E 1.4426950408889634f

typedef float v2f __attribute__((ext_vector_type(2)));

// ws layout (float offsets):
//   cnt   [0,     5000)    int   (zeroed by k_init)
//   base  [5000, 10001)    int   (pad to 10008)
//   rank  [10008,170008)   int
//   epak  [170008,490008)  int2 (src, w-bits) per bucketed edge
//   dis   [490008,495008)
//   tabG  [495008,509100)  packed PADDED tables (zeroed by k_init):
//     mz4   [0,2560)       float4[640] (LOG2E-scaled)
//     mh4   [2560,5120)    float4[640] (2*LOG2E-scaled)
//     bzh   [5120,6400)    float2[640] (betaz,betah)
//     wt    [6400,14080)   float4[3][640]: wt[q][d][j] = Whead[4q+j][d]
//     probs [14080,14092)

// zero cnt (5000 words) and tabG (14092 words)
__global__ void k_init(int* __restrict__ cnt, float* __restrict__ tabG) {
    int i = blockIdx.x * blockDim.x + threadIdx.x;
    if (i < 5000) cnt[i] = 0;
    else if (i < 19092) tabG[i - 5000] = 0.f;
}

// Fused: blocks [0,625) rank histogram (int atomic only);
//        blocks [625,...) weight composition into tabG (independent work).
#define CNT_BLOCKS 625
#define WB_WAVES 6132   // 6000 table + 12 probs + 120 wt-repack
__global__ __launch_bounds__(256) void k_count(
        const int* __restrict__ ei,
        int* __restrict__ cnt, int* __restrict__ rank,
        const float* __restrict__ Wz, const float* __restrict__ bz,
        const float* __restrict__ Wh, const float* __restrict__ bh,
        const float* __restrict__ Wlz, const float* __restrict__ blz,
        const float* __restrict__ Wlh, const float* __restrict__ blh,
        const float* __restrict__ att, const float* __restrict__ Whead,
        float* __restrict__ tabG) {
    int bid = blockIdx.x;
    int tid = threadIdx.x;
    if (bid < CNT_BLOCKS) {
        int e = bid * 256 + tid;
        if (e < NE) rank[e] = atomicAdd(&cnt[ei[NE + e]], 1);
        return;
    }
    int wid = (bid - CNT_BLOCKS) * 4 + (tid >> 6);
    int lane = tid & 63;
    if (wid >= WB_WAVES) return;

    if (wid < 6000) {
        const float* va;
        const float* vb;
        float scale, bias = 0.f;
        if (wid < 2400) {
            int f = wid / NC, d = wid % NC;
            va = Wz + f * NC; vb = Wlz + d * (2 * NC); scale = LOG2E;
        } else if (wid < 4800) {
            int j = wid - 2400;
            int f = j / NC, d = j % NC;
            va = Wh + f * NC; vb = Wlh + d * (2 * NC); scale = 2.0f * LOG2E;
        } else if (wid < 5400) {
            int d = wid - 4800;
            va = bz; vb = Wlz + d * (2 * NC); scale = LOG2E; bias = blz[d];
        } else {
            int d = wid - 5400;
            va = bh; vb = Wlh + d * (2 * NC); scale = 2.0f * LOG2E; bias = blh[d];
        }
        float s = 0.f;
        for (int c = lane; c < NC; c += 64) s = fmaf(va[c], vb[c], s);
#pragma unroll
        for (int off = 32; off > 0; off >>= 1) s += __shfl_down(s, off, 64);
        if (lane == 0) {
            float r = scale * (bias + s);
            if (wid < 2400) {
                int f = wid / NC, d = wid % NC;
                tabG[d * 4 + f] = r;
            } else if (wid < 4800) {
                int j = wid - 2400;
                int f = j / NC, d = j % NC;
                tabG[2560 + d * 4 + f] = r;
            } else if (wid < 5400) {
                tabG[5120 + (wid - 4800) * 2] = r;
            } else {
                tabG[5120 + (wid - 5400) * 2 + 1] = r;
            }
        }
    } else if (wid < 6012) {
        if (lane == 0) {
            int t = wid - 6000;
            float m = att[0];
            for (int k = 1; k < NT; ++k) m = fmaxf(m, att[k]);
            float ssum = 0.f;
            for (int k = 0; k < NT; ++k) ssum += __expf(att[k] - m);
            tabG[14080 + t] = __expf(att[t] - m) / ssum;
        }
    } else {
        int i = (wid - 6012) * 64 + lane;   // [0,7680)
        if (i < 7680) {
            int j = i & 3;
            int rest = i >> 2;          // [0,1920)
            int d = rest % NCP, q = rest / NCP;
            float v = (d < NC) ? Whead[(4 * q + j) * NC + d] : 0.f;
            tabG[6400 + i] = v;
        }
    }
}

// single-block exclusive scan of cnt -> base
#define SCAN_CHUNK 20
__global__ __launch_bounds__(256) void k_scan(const int* __restrict__ cnt,
                                              int* __restrict__ base) {
    __shared__ int part[256];
    int t = threadIdx.x;
    int start = t * SCAN_CHUNK;
    int s = 0;
#pragma unroll
    for (int k = 0; k < SCAN_CHUNK; ++k) {
        int idx = start + k;
        if (idx < NN) s += cnt[idx];
    }
    part[t] = s;
    __syncthreads();
    for (int off = 1; off < 256; off <<= 1) {
        int v = (t >= off) ? part[t - off] : 0;
        __syncthreads();
        part[t] += v;
        __syncthreads();
    }
    int running = (t == 0) ? 0 : part[t - 1];
#pragma unroll
    for (int k = 0; k < SCAN_CHUNK; ++k) {
        int idx = start + k;
        if (idx < NN) {
            base[idx] = running;
            running += cnt[idx];
        }
    }
    if (t == 255) base[NN] = part[255];
}

// deterministic-position scatter of packed (src, weight): one 8B store
__global__ void k_scatter(const int* __restrict__ ei, const float* __restrict__ w,
                          const int* __restrict__ base, const int* __restrict__ rank,
                          int2* __restrict__ epak) {
    int e = blockIdx.x * blockDim.x + threadIdx.x;
    if (e < NE) {
        int2 p; p.x = ei[e]; p.y = __float_as_int(w[e]);
        epak[base[ei[NE + e]] + rank[e]] = p;
    }
}

// per-node degree from packed edges (sequential reads), dis = rsqrt(1+deg)
__global__ __launch_bounds__(64) void k_deg_dis(const int2* __restrict__ epak,
                                                const int* __restrict__ base,
                                                float* __restrict__ dis) {
    int n = blockIdx.x;
    int lane = threadIdx.x;
    int b0 = base[n], b1 = base[n + 1];
    float s = 0.f;
    for (int j = b0 + lane; j < b1; j += 64) s += __int_as_float(epak[j].y);
#pragma unroll
    for (int off = 32; off > 0; off >>= 1) s += __shfl_down(s, off, 64);
    if (lane == 0) dis[n] = rsqrtf(1.0f + s);
}

// FUSED gather + gate + attention + head, 2 WAVES PER NODE.
// 2500 blocks x 4 waves = 2 nodes/block; wave pair (half=0,1) splits the
// node's edge range for gather (partials combined via LDS) and the d-range
// for the gate (half*320 + it*64 + lane, 5 iters). Doubles block count ->
// better occupancy ramp/tail + gather/gate phase overlap across blocks.
__global__ __launch_bounds__(256, 3) void k_node(
        const float* __restrict__ x, const float* __restrict__ dis,
        const int2* __restrict__ epak, const int* __restrict__ base,
        const float* __restrict__ tabG,
        const float* __restrict__ bhead, float* __restrict__ out) {
    __shared__ float aggS[4][FT];
    __shared__ float red[4][NT][16];
    int tid = threadIdx.x;
    int wid = __builtin_amdgcn_readfirstlane(tid >> 6);
    int lane = tid & 63;
    int pair = wid >> 1;   // 0,1 : node within block
    int half = wid & 1;    // 0,1 : edge/d half
    int n = blockIdx.x * 2 + pair;   // uniform

    // ---- phase 1: gather this wave's HALF of the edge range ----
    int b0 = base[n], b1 = base[n + 1];
    int mid = b0 + (((b1 - b0) >> 1) & ~3);   // 4-aligned split
    int s0 = half ? mid : b0;
    int s1 = half ? b1 : mid;
    float dn = dis[n];
    float acc = 0.f;
    if (half == 0 && lane < FT) acc = dn * x[n * FT + lane];
    int j = s0;
    for (; j + 3 < s1; j += 4) {
        int2 p0 = epak[j], p1 = epak[j + 1], p2 = epak[j + 2], p3 = epak[j + 3];
        float n0 = dis[p0.x] * __int_as_float(p0.y);
        float n1 = dis[p1.x] * __int_as_float(p1.y);
        float n2 = dis[p2.x] * __int_as_float(p2.y);
        float n3 = dis[p3.x] * __int_as_float(p3.y);
        if (lane < FT) {
            acc += n0 * x[p0.x * FT + lane];
            acc += n1 * x[p1.x * FT + lane];
            acc += n2 * x[p2.x * FT + lane];
            acc += n3 * x[p3.x * FT + lane];
        }
    }
    for (; j < s1; ++j) {
        int2 p0 = epak[j];
        float n0 = dis[p0.x] * __int_as_float(p0.y);
        if (lane < FT) acc += n0 * x[p0.x * FT + lane];
    }
    acc *= dn;   // each half scaled; halves sum to dn*(dn*x + sum nu*x)

    if (lane < FT) aggS[wid][lane] = acc;
    __syncthreads();
    float av = 0.f;
    if (lane < FT) av = aggS[2 * pair][lane] + aggS[2 * pair + 1][lane];

    // ---- broadcast combined agg row to wave-uniform scalars (SGPRs) ----
    v2f A2[24];
#pragma unroll
    for (int i = 0; i < 24; ++i) {
        A2[i].x = __int_as_float(__builtin_amdgcn_readlane(__float_as_int(av), 2 * i));
        A2[i].y = __int_as_float(__builtin_amdgcn_readlane(__float_as_int(av), 2 * i + 1));
    }

    // ---- phase 2: gate + attention + head over THIS WAVE'S d-half ----
    const float4* mz4 = (const float4*)tabG;
    const float4* mh4 = (const float4*)(tabG + 2560);
    const float2* bzh = (const float2*)(tabG + 5120);
    const float4* wt4 = (const float4*)(tabG + 6400);   // [q*640 + d]

    v2f pp[6];
#pragma unroll
    for (int tp = 0; tp < 6; ++tp) { pp[tp].x = tabG[14080 + 2 * tp]; pp[tp].y = tabG[14080 + 2 * tp + 1]; }

    float outp[NT];
#pragma unroll
    for (int t = 0; t < NT; ++t) outp[t] = 0.f;

#pragma unroll
    for (int it = 0; it < 5; ++it) {
        int dd = half * 320 + it * 64 + lane;   // < 640, pad rows zero -> r=0

        float4 mzv = mz4[dd];
        float4 mhv = mh4[dd];
        float2 bb = bzh[dd];

        v2f hacc; hacc.x = 0.f; hacc.y = 0.f;
#pragma unroll
        for (int tp = 0; tp < 6; ++tp) {
            v2f u; u.x = bb.x; u.y = bb.x;
            v2f v; v.x = bb.y; v.y = bb.y;
            u += A2[0 * 6 + tp] * mzv.x;
            u += A2[1 * 6 + tp] * mzv.y;
            u += A2[2 * 6 + tp] * mzv.z;
            u += A2[3 * 6 + tp] * mzv.w;
            v += A2[0 * 6 + tp] * mhv.x;
            v += A2[1 * 6 + tp] * mhv.y;
            v += A2[2 * 6 + tp] * mhv.z;
            v += A2[3 * 6 + tp] * mhv.w;
            v2f eu; eu.x = exp2f(u.x); eu.y = exp2f(u.y);
            v2f ev; ev.x = exp2f(v.x); ev.y = exp2f(v.y);
            v2f den = (eu + 1.f) * (ev + 1.f);
            v2f rd; rd.x = __builtin_amdgcn_rcpf(den.x); rd.y = __builtin_amdgcn_rcpf(den.y);
            v2f num = pp[tp] * (ev - 1.f);
            hacc += num * rd;
        }
        float r = fmaxf(hacc.x + hacc.y, 0.f);

        float4 w0 = wt4[0 * NCP + dd], w1 = wt4[1 * NCP + dd], w2 = wt4[2 * NCP + dd];
        outp[0]  = fmaf(r, w0.x, outp[0]);   outp[1]  = fmaf(r, w0.y, outp[1]);
        outp[2]  = fmaf(r, w0.z, outp[2]);   outp[3]  = fmaf(r, w0.w, outp[3]);
        outp[4]  = fmaf(r, w1.x, outp[4]);   outp[5]  = fmaf(r, w1.y, outp[5]);
        outp[6]  = fmaf(r, w1.z, outp[6]);   outp[7]  = fmaf(r, w1.w, outp[7]);
        outp[8]  = fmaf(r, w2.x, outp[8]);   outp[9]  = fmaf(r, w2.y, outp[9]);
        outp[10] = fmaf(r, w2.z, outp[10]);  outp[11] = fmaf(r, w2.w, outp[11]);
    }

    // 2-step shuffle -> red[wid][t][0..16); barrier; half 0 sums both halves
#pragma unroll
    for (int t = 0; t < NT; ++t) {
        float v = outp[t];
        v += __shfl_xor(v, 32, 64);
        v += __shfl_xor(v, 16, 64);
        if (lane < 16) red[wid][t][lane] = v;
    }
    __syncthreads();
    if (half == 0 && lane < NT) {
        const float4* rowA = (const float4*)red[2 * pair][lane];
        const float4* rowB = (const float4*)red[2 * pair + 1][lane];
        float4 a = rowA[0], b = rowA[1], c = rowA[2], d = rowA[3];
        float4 e = rowB[0], f = rowB[1], g = rowB[2], h = rowB[3];
        float s = ((a.x + a.y) + (a.z + a.w)) + ((b.x + b.y) + (b.z + b.w))
                + ((c.x + c.y) + (c.z + c.w)) + ((d.x + d.y) + (d.z + d.w))
                + ((e.x + e.y) + (e.z + e.w)) + ((f.x + f.y) + (f.z + f.w))
                + ((g.x + g.y) + (g.z + g.w)) + ((h.x + h.y) + (h.z + h.w));
        out[n * NT + lane] = s + bhead[lane];
    }
}

extern "C" void kernel_launch(void* const* d_in, const int* in_sizes, int n_in,
                              void* d_out, int out_size, void* d_ws, size_t ws_size,
                              hipStream_t stream) {
    const float* x     = (const float*)d_in[0];
    const int*   ei    = (const int*)d_in[1];
    const float* ea    = (const float*)d_in[2];
    const float* Wz    = (const float*)d_in[3];
    const float* bz    = (const float*)d_in[4];
    const float* Wh    = (const float*)d_in[7];
    const float* bh    = (const float*)d_in[8];
    const float* Wlz   = (const float*)d_in[9];
    const float* blz   = (const float*)d_in[10];
    const float* Wlh   = (const float*)d_in[13];
    const float* blh   = (const float*)d_in[14];
    const float* att   = (const float*)d_in[15];
    const float* Whead = (const float*)d_in[16];
    const float* bhead = (const float*)d_in[17];
    float* out = (float*)d_out;

    float* ws   = (float*)d_ws;
    int*   cnt  = (int*)ws;                 // [0,5000)
    int*   base = (int*)(ws + 5000);        // [5000,10008)
    int*   rank = (int*)(ws + 10008);
    int2*  epak = (int2*)(ws + 170008);
    float* dis  = ws + 490008;
    float* tabG = ws + 495008;

    k_init<<<(19092 + 255) / 256, 256, 0, stream>>>(cnt, tabG);
    k_count<<<CNT_BLOCKS + (WB_WAVES + 3) / 4, 256, 0, stream>>>(
        ei, cnt, rank,
        Wz, bz, Wh, bh, Wlz, blz, Wlh, blh, att, Whead, tabG);
    k_scan<<<1, 256, 0, stream>>>(cnt, base);
    k_scatter<<<(NE + 255) / 256, 256, 0, stream>>>(ei, ea, base, rank, epak);
    k_deg_dis<<<NN, 64, 0, stream>>>(epak, base, dis);
    k_node<<<NN / 2, 256, 0, stream>>>(x, dis, epak, base, tabG, bhead, out);
}

// Round 24
// 72.114 us; speedup vs baseline: 1.0493x; 1.0037x over previous
//
#include <hip/hip_runtime.h>

#define NN 5000
#define NF 4
#define NT 12
#define NC 600
#define NCP 640   // padded d-extent (zero pad -> r=0, no predication)
#define NE 160000
#define FT 48   // NF*NT
#define LOG2E 1.4426950408889634f

typedef float v2f __attribute__((ext_vector_type(2)));

// ws layout (float offsets):
//   cnt   [0,     5000)    int   (zeroed by k_init)
//   base  [5000, 10001)    int   (pad to 10008)
//   rank  [10008,170008)   int
//   epak  [170008,490008)  int2 (src, w-bits) per bucketed edge
//   dis   [490008,495008)
//   tabG  [495008,509100)  packed PADDED tables (zeroed by k_init):
//     mz4   [0,2560)       float4[640] (LOG2E-scaled)
//     mh4   [2560,5120)    float4[640] (2*LOG2E-scaled)
//     bzh   [5120,6400)    float2[640] (betaz,betah)
//     wt    [6400,14080)   float4[3][640]: wt[q][d][j] = Whead[4q+j][d]
//     probs [14080,14092)

// zero cnt (5000 words) and tabG (14092 words)
__global__ void k_init(int* __restrict__ cnt, float* __restrict__ tabG) {
    int i = blockIdx.x * blockDim.x + threadIdx.x;
    if (i < 5000) cnt[i] = 0;
    else if (i < 19092) tabG[i - 5000] = 0.f;
}

// Fused: blocks [0,625) rank histogram (int atomic only);
//        blocks [625,...) weight composition into tabG (independent work).
#define CNT_BLOCKS 625
#define WB_WAVES 6132   // 6000 table + 12 probs + 120 wt-repack
__global__ __launch_bounds__(256) void k_count(
        const int* __restrict__ ei,
        int* __restrict__ cnt, int* __restrict__ rank,
        const float* __restrict__ Wz, const float* __restrict__ bz,
        const float* __restrict__ Wh, const float* __restrict__ bh,
        const float* __restrict__ Wlz, const float* __restrict__ blz,
        const float* __restrict__ Wlh, const float* __restrict__ blh,
        const float* __restrict__ att, const float* __restrict__ Whead,
        float* __restrict__ tabG) {
    int bid = blockIdx.x;
    int tid = threadIdx.x;
    if (bid < CNT_BLOCKS) {
        int e = bid * 256 + tid;
        if (e < NE) rank[e] = atomicAdd(&cnt[ei[NE + e]], 1);
        return;
    }
    int wid = (bid - CNT_BLOCKS) * 4 + (tid >> 6);
    int lane = tid & 63;
    if (wid >= WB_WAVES) return;

    if (wid < 6000) {
        const float* va;
        const float* vb;
        float scale, bias = 0.f;
        if (wid < 2400) {
            int f = wid / NC, d = wid % NC;
            va = Wz + f * NC; vb = Wlz + d * (2 * NC); scale = LOG2E;
        } else if (wid < 4800) {
            int j = wid - 2400;
            int f = j / NC, d = j % NC;
            va = Wh + f * NC; vb = Wlh + d * (2 * NC); scale = 2.0f * LOG2E;
        } else if (wid < 5400) {
            int d = wid - 4800;
            va = bz; vb = Wlz + d * (2 * NC); scale = LOG2E; bias = blz[d];
        } else {
            int d = wid - 5400;
            va = bh; vb = Wlh + d * (2 * NC); scale = 2.0f * LOG2E; bias = blh[d];
        }
        float s = 0.f;
        for (int c = lane; c < NC; c += 64) s = fmaf(va[c], vb[c], s);
#pragma unroll
        for (int off = 32; off > 0; off >>= 1) s += __shfl_down(s, off, 64);
        if (lane == 0) {
            float r = scale * (bias + s);
            if (wid < 2400) {
                int f = wid / NC, d = wid % NC;
                tabG[d * 4 + f] = r;
            } else if (wid < 4800) {
                int j = wid - 2400;
                int f = j / NC, d = j % NC;
                tabG[2560 + d * 4 + f] = r;
            } else if (wid < 5400) {
                tabG[5120 + (wid - 4800) * 2] = r;
            } else {
                tabG[5120 + (wid - 5400) * 2 + 1] = r;
            }
        }
    } else if (wid < 6012) {
        if (lane == 0) {
            int t = wid - 6000;
            float m = att[0];
            for (int k = 1; k < NT; ++k) m = fmaxf(m, att[k]);
            float ssum = 0.f;
            for (int k = 0; k < NT; ++k) ssum += __expf(att[k] - m);
            tabG[14080 + t] = __expf(att[t] - m) / ssum;
        }
    } else {
        int i = (wid - 6012) * 64 + lane;   // [0,7680)
        if (i < 7680) {
            int j = i & 3;
            int rest = i >> 2;          // [0,1920)
            int d = rest % NCP, q = rest / NCP;
            float v = (d < NC) ? Whead[(4 * q + j) * NC + d] : 0.f;
            tabG[6400 + i] = v;
        }
    }
}

// single-block exclusive scan of cnt -> base
#define SCAN_CHUNK 20
__global__ __launch_bounds__(256) void k_scan(const int* __restrict__ cnt,
                                              int* __restrict__ base) {
    __shared__ int part[256];
    int t = threadIdx.x;
    int start = t * SCAN_CHUNK;
    int s = 0;
#pragma unroll
    for (int k = 0; k < SCAN_CHUNK; ++k) {
        int idx = start + k;
        if (idx < NN) s += cnt[idx];
    }
    part[t] = s;
    __syncthreads();
    for (int off = 1; off < 256; off <<= 1) {
        int v = (t >= off) ? part[t - off] : 0;
        __syncthreads();
        part[t] += v;
        __syncthreads();
    }
    int running = (t == 0) ? 0 : part[t - 1];
#pragma unroll
    for (int k = 0; k < SCAN_CHUNK; ++k) {
        int idx = start + k;
        if (idx < NN) {
            base[idx] = running;
            running += cnt[idx];
        }
    }
    if (t == 255) base[NN] = part[255];
}

// deterministic-position scatter of packed (src, weight): one 8B store
__global__ void k_scatter(const int* __restrict__ ei, const float* __restrict__ w,
                          const int* __restrict__ base, const int* __restrict__ rank,
                          int2* __restrict__ epak) {
    int e = blockIdx.x * blockDim.x + threadIdx.x;
    if (e < NE) {
        int2 p; p.x = ei[e]; p.y = __float_as_int(w[e]);
        epak[base[ei[NE + e]] + rank[e]] = p;
    }
}

// per-node degree from packed edges (sequential reads), dis = rsqrt(1+deg)
__global__ __launch_bounds__(64) void k_deg_dis(const int2* __restrict__ epak,
                                                const int* __restrict__ base,
                                                float* __restrict__ dis) {
    int n = blockIdx.x;
    int lane = threadIdx.x;
    int b0 = base[n], b1 = base[n + 1];
    float s = 0.f;
    for (int j = b0 + lane; j < b1; j += 64) s += __int_as_float(epak[j].y);
#pragma unroll
    for (int off = 32; off > 0; off >>= 1) s += __shfl_down(s, off, 64);
    if (lane == 0) dis[n] = rsqrtf(1.0f + s);
}

// FUSED gather + gate + attention + head, 2 WAVES PER NODE (R23 structure).
// Gate-phase change: PRELOAD all 5 d-iterations' mz/mh/bzh fragments into
// registers up-front (50 VGPRs persistent) so their L1 latency is exposed
// once, not 5x. wt stays in-loop (transient). Demand ~80 < lb(256,3) 84-cap.
__global__ __launch_bounds__(256, 3) void k_node(
        const float* __restrict__ x, const float* __restrict__ dis,
        const int2* __restrict__ epak, const int* __restrict__ base,
        const float* __restrict__ tabG,
        const float* __restrict__ bhead, float* __restrict__ out) {
    __shared__ float aggS[4][FT];
    __shared__ float red[4][NT][16];
    int tid = threadIdx.x;
    int wid = __builtin_amdgcn_readfirstlane(tid >> 6);
    int lane = tid & 63;
    int pair = wid >> 1;   // 0,1 : node within block
    int half = wid & 1;    // 0,1 : edge/d half
    int n = blockIdx.x * 2 + pair;   // uniform

    // ---- phase 1: gather this wave's HALF of the edge range ----
    int b0 = base[n], b1 = base[n + 1];
    int mid = b0 + (((b1 - b0) >> 1) & ~3);   // 4-aligned split
    int s0 = half ? mid : b0;
    int s1 = half ? b1 : mid;
    float dn = dis[n];
    float acc = 0.f;
    if (half == 0 && lane < FT) acc = dn * x[n * FT + lane];
    int j = s0;
    for (; j + 3 < s1; j += 4) {
        int2 p0 = epak[j], p1 = epak[j + 1], p2 = epak[j + 2], p3 = epak[j + 3];
        float n0 = dis[p0.x] * __int_as_float(p0.y);
        float n1 = dis[p1.x] * __int_as_float(p1.y);
        float n2 = dis[p2.x] * __int_as_float(p2.y);
        float n3 = dis[p3.x] * __int_as_float(p3.y);
        if (lane < FT) {
            acc += n0 * x[p0.x * FT + lane];
            acc += n1 * x[p1.x * FT + lane];
            acc += n2 * x[p2.x * FT + lane];
            acc += n3 * x[p3.x * FT + lane];
        }
    }
    for (; j < s1; ++j) {
        int2 p0 = epak[j];
        float n0 = dis[p0.x] * __int_as_float(p0.y);
        if (lane < FT) acc += n0 * x[p0.x * FT + lane];
    }
    acc *= dn;   // each half scaled; halves sum to dn*(dn*x + sum nu*x)

    if (lane < FT) aggS[wid][lane] = acc;
    __syncthreads();
    float av = 0.f;
    if (lane < FT) av = aggS[2 * pair][lane] + aggS[2 * pair + 1][lane];

    // ---- broadcast combined agg row to wave-uniform scalars (SGPRs) ----
    v2f A2[24];
#pragma unroll
    for (int i = 0; i < 24; ++i) {
        A2[i].x = __int_as_float(__builtin_amdgcn_readlane(__float_as_int(av), 2 * i));
        A2[i].y = __int_as_float(__builtin_amdgcn_readlane(__float_as_int(av), 2 * i + 1));
    }

    // ---- phase 2: gate + attention + head over THIS WAVE'S d-half ----
    const float4* mz4 = (const float4*)tabG;
    const float4* mh4 = (const float4*)(tabG + 2560);
    const float2* bzh = (const float2*)(tabG + 5120);
    const float4* wt4 = (const float4*)(tabG + 6400);   // [q*640 + d]

    v2f pp[6];
#pragma unroll
    for (int tp = 0; tp < 6; ++tp) { pp[tp].x = tabG[14080 + 2 * tp]; pp[tp].y = tabG[14080 + 2 * tp + 1]; }

    // PRELOAD all 5 iterations' gate-table fragments (issues 15 loads
    // back-to-back; one latency exposure). 50 persistent VGPRs.
    float4 MZ[5], MH[5];
    float2 BB[5];
#pragma unroll
    for (int it = 0; it < 5; ++it) {
        int dd = half * 320 + it * 64 + lane;
        MZ[it] = mz4[dd];
        MH[it] = mh4[dd];
        BB[it] = bzh[dd];
    }

    float outp[NT];
#pragma unroll
    for (int t = 0; t < NT; ++t) outp[t] = 0.f;

#pragma unroll
    for (int it = 0; it < 5; ++it) {
        int dd = half * 320 + it * 64 + lane;   // < 640, pad rows zero -> r=0

        float4 mzv = MZ[it];
        float4 mhv = MH[it];
        float2 bb = BB[it];

        v2f hacc; hacc.x = 0.f; hacc.y = 0.f;
#pragma unroll
        for (int tp = 0; tp < 6; ++tp) {
            v2f u; u.x = bb.x; u.y = bb.x;
            v2f v; v.x = bb.y; v.y = bb.y;
            u += A2[0 * 6 + tp] * mzv.x;
            u += A2[1 * 6 + tp] * mzv.y;
            u += A2[2 * 6 + tp] * mzv.z;
            u += A2[3 * 6 + tp] * mzv.w;
            v += A2[0 * 6 + tp] * mhv.x;
            v += A2[1 * 6 + tp] * mhv.y;
            v += A2[2 * 6 + tp] * mhv.z;
            v += A2[3 * 6 + tp] * mhv.w;
            v2f eu; eu.x = exp2f(u.x); eu.y = exp2f(u.y);
            v2f ev; ev.x = exp2f(v.x); ev.y = exp2f(v.y);
            v2f den = (eu + 1.f) * (ev + 1.f);
            v2f rd; rd.x = __builtin_amdgcn_rcpf(den.x); rd.y = __builtin_amdgcn_rcpf(den.y);
            v2f num = pp[tp] * (ev - 1.f);
            hacc += num * rd;
        }
        float r = fmaxf(hacc.x + hacc.y, 0.f);

        float4 w0 = wt4[0 * NCP + dd], w1 = wt4[1 * NCP + dd], w2 = wt4[2 * NCP + dd];
        outp[0]  = fmaf(r, w0.x, outp[0]);   outp[1]  = fmaf(r, w0.y, outp[1]);
        outp[2]  = fmaf(r, w0.z, outp[2]);   outp[3]  = fmaf(r, w0.w, outp[3]);
        outp[4]  = fmaf(r, w1.x, outp[4]);   outp[5]  = fmaf(r, w1.y, outp[5]);
        outp[6]  = fmaf(r, w1.z, outp[6]);   outp[7]  = fmaf(r, w1.w, outp[7]);
        outp[8]  = fmaf(r, w2.x, outp[8]);   outp[9]  = fmaf(r, w2.y, outp[9]);
        outp[10] = fmaf(r, w2.z, outp[10]);  outp[11] = fmaf(r, w2.w, outp[11]);
    }

    // 2-step shuffle -> red[wid][t][0..16); barrier; half 0 sums both halves
#pragma unroll
    for (int t = 0; t < NT; ++t) {
        float v = outp[t];
        v += __shfl_xor(v, 32, 64);
        v += __shfl_xor(v, 16, 64);
        if (lane < 16) red[wid][t][lane] = v;
    }
    __syncthreads();
    if (half == 0 && lane < NT) {
        const float4* rowA = (const float4*)red[2 * pair][lane];
        const float4* rowB = (const float4*)red[2 * pair + 1][lane];
        float4 a = rowA[0], b = rowA[1], c = rowA[2], d = rowA[3];
        float4 e = rowB[0], f = rowB[1], g = rowB[2], h = rowB[3];
        float s = ((a.x + a.y) + (a.z + a.w)) + ((b.x + b.y) + (b.z + b.w))
                + ((c.x + c.y) + (c.z + c.w)) + ((d.x + d.y) + (d.z + d.w))
                + ((e.x + e.y) + (e.z + e.w)) + ((f.x + f.y) + (f.z + f.w))
                + ((g.x + g.y) + (g.z + g.w)) + ((h.x + h.y) + (h.z + h.w));
        out[n * NT + lane] = s + bhead[lane];
    }
}

extern "C" void kernel_launch(void* const* d_in, const int* in_sizes, int n_in,
                              void* d_out, int out_size, void* d_ws, size_t ws_size,
                              hipStream_t stream) {
    const float* x     = (const float*)d_in[0];
    const int*   ei    = (const int*)d_in[1];
    const float* ea    = (const float*)d_in[2];
    const float* Wz    = (const float*)d_in[3];
    const float* bz    = (const float*)d_in[4];
    const float* Wh    = (const float*)d_in[7];
    const float* bh    = (const float*)d_in[8];
    const float* Wlz   = (const float*)d_in[9];
    const float* blz   = (const float*)d_in[10];
    const float* Wlh   = (const float*)d_in[13];
    const float* blh   = (const float*)d_in[14];
    const float* att   = (const float*)d_in[15];
    const float* Whead = (const float*)d_in[16];
    const float* bhead = (const float*)d_in[17];
    float* out = (float*)d_out;

    float* ws   = (float*)d_ws;
    int*   cnt  = (int*)ws;                 // [0,5000)
    int*   base = (int*)(ws + 5000);        // [5000,10008)
    int*   rank = (int*)(ws + 10008);
    int2*  epak = (int2*)(ws + 170008);
    float* dis  = ws + 490008;
    float* tabG = ws + 495008;

    k_init<<<(19092 + 255) / 256, 256, 0, stream>>>(cnt, tabG);
    k_count<<<CNT_BLOCKS + (WB_WAVES + 3) / 4, 256, 0, stream>>>(
        ei, cnt, rank,
        Wz, bz, Wh, bh, Wlz, blz, Wlh, blh, att, Whead, tabG);
    k_scan<<<1, 256, 0, stream>>>(cnt, base);
    k_scatter<<<(NE + 255) / 256, 256, 0, stream>>>(ei, ea, base, rank, epak);
    k_deg_dis<<<NN, 64, 0, stream>>>(epak, base, dis);
    k_node<<<NN / 2, 256, 0, stream>>>(x, dis, epak, base, tabG, bhead, out);
}